// Round 10
// baseline (784.364 us; speedup 1.0000x reference)
//
#include <hip/hip_runtime.h>
#include <hip/hip_fp16.h>

typedef _Float16 f16x4 __attribute__((ext_vector_type(4)));
typedef _Float16 f16x8 __attribute__((ext_vector_type(8)));
typedef float    f32x4 __attribute__((ext_vector_type(4)));

#define TBD 67108864ull   // T*B*D
#define BD  1048576ull    // B*D

#define ASM_VMCNT(N) asm volatile("s_waitcnt vmcnt(" #N ")" ::: "memory")
#define ASM_LGKM(N)  asm volatile("s_waitcnt lgkmcnt(" #N ")" ::: "memory")
#define BARRIER()    __builtin_amdgcn_s_barrier()
#define MFMA(a,b,c)  __builtin_amdgcn_mfma_f32_16x16x32_f16((a),(b),(c),0,0,0)

// ---------------- Kernel 1: se = (pred-true)^2 -> fp16 ----------------
__global__ __launch_bounds__(256) void se_split_k(const float* __restrict__ pred,
                                                  const float* __restrict__ tru,
                                                  _Float16* __restrict__ hi) {
  size_t stride = (size_t)gridDim.x * 1024;
  for (size_t i = ((size_t)blockIdx.x * 256 + threadIdx.x) * 4; i < TBD; i += stride) {
    float4 p = *(const float4*)(pred + i);
    float4 t = *(const float4*)(tru + i);
    f16x4 h;
    h[0] = (_Float16)((p.x - t.x) * (p.x - t.x));
    h[1] = (_Float16)((p.y - t.y) * (p.y - t.y));
    h[2] = (_Float16)((p.z - t.z) * (p.z - t.z));
    h[3] = (_Float16)((p.w - t.w) * (p.w - t.w));
    *(f16x4*)(hi + i) = h;
  }
}

// ---------------- Kernel 2: W -> fp16 ----------------
__global__ __launch_bounds__(256) void w_split_k(const float* __restrict__ W,
                                                 _Float16* __restrict__ hi) {
  size_t i = ((size_t)blockIdx.x * 256 + threadIdx.x) * 4;  // covers 1048576 exactly
  float4 x = *(const float4*)(W + i);
  f16x4 h;
  h[0] = (_Float16)x.x; h[1] = (_Float16)x.y; h[2] = (_Float16)x.z; h[3] = (_Float16)x.w;
  *(f16x4*)(hi + i) = h;
}

// ---------------- Kernel 3: logits(fp16) = SE @ Wh^T + b  (single-pass fp16 MFMA) -----
// M=65536, N=1024, K=1024. Block-tile 128x256, BK=32, 4 waves (2M x 2N),
// wave-tile 64x128. 3 blocks/CU (144KB LDS, launch_bounds(256,3)): 3-wave TLP/SIMD
// hides L2/L3 staging latency (r9 lesson: 2-wave TLP left a ~2x gap over LDS floor).
// fp16 C-write halves epilogue traffic (precision: logit abs err ~1.5e-3 -> negligible).
// LDS super-row layout (r9-verified 0 conflicts): srow = rows {2s,2s+1}, 128B = 8x16B
// slots; logical ls = kchunk + 4*(row&1); physical = ls ^ (srow&7).
// Buffer = A [64 srows][128B] (8KB) + B [128 srows][128B] (16KB) = 24KB; dbuf 48KB.
// K-loop (r3/r8 cadence): 12 ds_reads; lgkm(6/4/2/0) fences; all-reads barrier;
// stage 6 loads for t+2; counted vmcnt(6), never drained in the loop.

#define GL2_A(dstb, kof)                                                          \
  _Pragma("unroll")                                                               \
  for (int q = 0; q < 2; ++q)                                                     \
    __builtin_amdgcn_global_load_lds(                                             \
        (const __attribute__((address_space(1))) void*)(aSrc[q] + (kof)),         \
        (__attribute__((address_space(3))) void*)((dstb) + q * 4096 + tid * 16),  \
        16, 0, 0);

#define GL4_B(dstb, kof)                                                          \
  _Pragma("unroll")                                                               \
  for (int q = 0; q < 4; ++q)                                                     \
    __builtin_amdgcn_global_load_lds(                                             \
        (const __attribute__((address_space(1))) void*)(bSrc[q] + (kof)),         \
        (__attribute__((address_space(3))) void*)((dstb) + 8192 + q * 4096 + tid * 16), \
        16, 0, 0);

// 8 MFMAs per cluster: 8 independent accumulators (4 fi x 2 fj).
#define MCL(j0, B0, B1)                                  \
  __builtin_amdgcn_s_setprio(1);                         \
  acc[0][(j0)]   = MFMA(a0, B0, acc[0][(j0)]);           \
  acc[1][(j0)]   = MFMA(a1, B0, acc[1][(j0)]);           \
  acc[2][(j0)]   = MFMA(a2, B0, acc[2][(j0)]);           \
  acc[3][(j0)]   = MFMA(a3, B0, acc[3][(j0)]);           \
  acc[0][(j0)+1] = MFMA(a0, B1, acc[0][(j0)+1]);         \
  acc[1][(j0)+1] = MFMA(a1, B1, acc[1][(j0)+1]);         \
  acc[2][(j0)+1] = MFMA(a2, B1, acc[2][(j0)+1]);         \
  acc[3][(j0)+1] = MFMA(a3, B1, acc[3][(j0)+1]);         \
  __builtin_amdgcn_s_setprio(0);

#define LD(buf, off) (*(const f16x8*)((buf) + (off)))

__global__ __launch_bounds__(256, 3) void gemm_logits_k(
    const _Float16* __restrict__ Ah, const _Float16* __restrict__ Wh,
    const float* __restrict__ bias, _Float16* __restrict__ C) {
  __shared__ uint4 lds4[3072];  // 48 KiB
  char* lds = (char*)lds4;
  const int tid = threadIdx.x;
  const int lane = tid & 63;
  const int wid = tid >> 6;          // 0..3
  const int wm = wid >> 1;           // 0..1 (M)
  const int wn = wid & 1;            // 0..1 (N)

  // XCD-aware bijective swizzle: 2048 blocks, 8 XCDs, 256 per XCD.
  const int bid = blockIdx.x;
  const int wgid = (bid & 7) * 256 + (bid >> 3);
  const int bm = wgid >> 2, bn = wgid & 3;   // 512 M-tiles x 4 N-tiles
  const int row0 = bm * 128, col0 = bn * 256;

  // Staging sources (inverse of the super-row swizzle). A: 2 chunks; B: 4 chunks.
  const _Float16* aSrc[2];
  const _Float16* bSrc[4];
#pragma unroll
  for (int q = 0; q < 2; ++q) {
    int p = q * 4096 + tid * 16;      // byte offset in A region (8KB)
    int srow = p >> 7;                // 0..63
    int s = (p >> 4) & 7;             // physical slot
    int sig = s ^ (srow & 7);         // logical slot
    int row = 2 * srow + (sig >> 2);
    aSrc[q] = Ah + ((size_t)(row0 + row) * 1024 + (size_t)(sig & 3) * 8);
  }
#pragma unroll
  for (int q = 0; q < 4; ++q) {
    int p = q * 4096 + tid * 16;      // byte offset in B region (16KB)
    int srow = p >> 7;                // 0..127
    int s = (p >> 4) & 7;
    int sig = s ^ (srow & 7);
    int row = 2 * srow + (sig >> 2);
    bSrc[q] = Wh + ((size_t)(col0 + row) * 1024 + (size_t)(sig & 3) * 8);
  }

  // Fragment read offsets. 16x16x32 A-op: lane -> row (lane&15), k-chunk u=lane>>4.
  const int u = lane >> 4;             // 0..3
  const int hr = (lane & 15) >> 1;     // srow low bits 0..7
  const int ls = u + 4 * (lane & 1);   // logical slot
  const int aoff = (wm * 32 + hr) * 128 + ((ls ^ hr) * 16);           // + fi*1024
  const int boff = 8192 + (wn * 64 + hr) * 128 + ((ls ^ hr) * 16);    // + fj*1024

  f32x4 acc[4][8] = {};

  // Prologue: tile 0 -> buf0, tile 1 -> buf1; vmcnt(6) -> tile 0 resident.
  char* buf0 = lds;
  char* buf1 = lds + 24576;
  GL2_A(buf0, 0)
  GL4_B(buf0, 0)
  GL2_A(buf1, 32)
  GL4_B(buf1, 32)
  ASM_VMCNT(6);
  BARRIER();

#pragma unroll 1
  for (int t = 0; t < 32; ++t) {
    char* ldsb = lds + (t & 1) * 24576;
    const int tt = (t + 2 < 32) ? t + 2 : 31;   // dummy tail reload keeps vmcnt cadence
    const size_t kof = (size_t)tt * 32;

    // 12 ds_reads: A (4) then B (8)
    f16x8 a0 = LD(ldsb, aoff + 0 * 1024);
    f16x8 a1 = LD(ldsb, aoff + 1 * 1024);
    f16x8 a2 = LD(ldsb, aoff + 2 * 1024);
    f16x8 a3 = LD(ldsb, aoff + 3 * 1024);
    f16x8 b0 = LD(ldsb, boff + 0 * 1024);
    f16x8 b1 = LD(ldsb, boff + 1 * 1024);
    f16x8 b2 = LD(ldsb, boff + 2 * 1024);
    f16x8 b3 = LD(ldsb, boff + 3 * 1024);
    f16x8 b4 = LD(ldsb, boff + 4 * 1024);
    f16x8 b5 = LD(ldsb, boff + 5 * 1024);
    f16x8 b6 = LD(ldsb, boff + 6 * 1024);
    f16x8 b7 = LD(ldsb, boff + 7 * 1024);
    ASM_LGKM(6);               // A + b0,b1 resident
    MCL(0, b0, b1)
    ASM_LGKM(4);               // b2,b3
    MCL(2, b2, b3)
    ASM_LGKM(2);               // b4,b5
    MCL(4, b4, b5)
    ASM_LGKM(0);               // all reads of ldsb done
    BARRIER();                 // every wave done reading -> safe to overwrite
    GL2_A(ldsb, kof)           // stage tile t+2 (6 loads)
    GL4_B(ldsb, kof)
    MCL(6, b6, b7)
    ASM_VMCNT(6);              // tile t+1's 6 loads landed (t+2's 6 in flight)
    BARRIER();
  }
  ASM_VMCNT(0);    // drain tail dummy loads

  // Epilogue: C[i,j] = fp16(acc + bias[j]).  C/D: col=lane&15, row=(lane>>4)*4+q.
#pragma unroll
  for (int fj = 0; fj < 8; ++fj) {
    int c = col0 + wn * 128 + fj * 16 + (lane & 15);
    float bj = bias[c];
#pragma unroll
    for (int fi = 0; fi < 4; ++fi) {
      int r = row0 + wm * 64 + fi * 16 + u * 4;
#pragma unroll
      for (int q = 0; q < 4; ++q)
        C[(size_t)(r + q) * 1024 + c] = (_Float16)(acc[fi][fj][q] + bj);
    }
  }
}

// ---------------- Kernel 4: fused softmax + gating + loss accumulation ----------------
__global__ __launch_bounds__(256) void softmax_loss_k(const _Float16* __restrict__ logits,
                                                      const _Float16* __restrict__ hi,
                                                      float* __restrict__ out) {
  const int b = blockIdx.x;            // 0..1023
  const int tid = threadIdx.x, lane = tid & 63, wid = tid >> 6;
  __shared__ float red[8];
  float4 wprev = make_float4(1.f, 1.f, 1.f, 1.f);
  float4 lacc  = make_float4(0.f, 0.f, 0.f, 0.f);

  size_t base = (size_t)b * 1024;      // row (t=0, b)
  f16x4 xh = ((const f16x4*)(logits + base))[tid];
  f16x4 h  = ((const f16x4*)(hi + base))[tid];

#pragma unroll 1
  for (int t = 0; t < 64; ++t) {
    float4 se;
    se.x = (float)h[0];
    se.y = (float)h[1];
    se.z = (float)h[2];
    se.w = (float)h[3];
    lacc.x += wprev.x * se.x;
    lacc.y += wprev.y * se.y;
    lacc.z += wprev.z * se.z;
    lacc.w += wprev.w * se.w;

    int tn = (t + 1 < 64) ? t + 1 : t;
    size_t nbase = ((size_t)tn * 1024 + (size_t)b) * 1024;
    f16x4 xn = ((const f16x4*)(logits + nbase))[tid];
    f16x4 hn = ((const f16x4*)(hi + nbase))[tid];

    float4 x;
    x.x = (float)xh[0]; x.y = (float)xh[1]; x.z = (float)xh[2]; x.w = (float)xh[3];
    float m = fmaxf(fmaxf(x.x, x.y), fmaxf(x.z, x.w));
#pragma unroll
    for (int o = 32; o >= 1; o >>= 1) m = fmaxf(m, __shfl_xor(m, o, 64));
    if (lane == 0) red[wid] = m;
    __syncthreads();
    m = fmaxf(fmaxf(red[0], red[1]), fmaxf(red[2], red[3]));
    float e0 = __expf(x.x - m), e1 = __expf(x.y - m), e2 = __expf(x.z - m), e3 = __expf(x.w - m);
    float s = (e0 + e1) + (e2 + e3);
#pragma unroll
    for (int o = 32; o >= 1; o >>= 1) s += __shfl_xor(s, o, 64);
    if (lane == 0) red[4 + wid] = s;
    __syncthreads();
    s = (red[4] + red[5]) + (red[6] + red[7]);
    float inv = 1.0f / s;

    wprev.x = se.x * e0 * inv;
    wprev.y = se.y * e1 * inv;
    wprev.z = se.z * e2 * inv;
    wprev.w = se.w * e3 * inv;

    xh = xn; h = hn;
  }
  ((float4*)(out + (size_t)b * 1024))[tid] = lacc;
}

extern "C" void kernel_launch(void* const* d_in, const int* in_sizes, int n_in,
                              void* d_out, int out_size, void* d_ws, size_t ws_size,
                              hipStream_t stream) {
  const float* pred = (const float*)d_in[0];
  const float* tru  = (const float*)d_in[1];
  const float* W    = (const float*)d_in[2];
  const float* bias = (const float*)d_in[3];
  float* out = (float*)d_out;

  char* ws = (char*)d_ws;
  _Float16* se_hi  = (_Float16*)(ws);                    // 128 MB
  _Float16* logits = (_Float16*)(ws + 134217728ull);     // 128 MB (fp16)
  _Float16* W_hi   = (_Float16*)(ws + 268435456ull);     // 2 MB

  se_split_k<<<2048, 256, 0, stream>>>(pred, tru, se_hi);
  w_split_k<<<1024, 256, 0, stream>>>(W, W_hi);
  gemm_logits_k<<<2048, 256, 0, stream>>>(se_hi, W_hi, bias, logits);
  softmax_loss_k<<<1024, 256, 0, stream>>>(logits, se_hi, out);
}